// Round 1
// baseline (86.603 us; speedup 1.0000x reference)
//
#include <hip/hip_runtime.h>

// MeanAggregator: out[b, :] = mean_{s<10} features[idx[b,s], :]
// features: float32 [1'000'000, 128]; idx: int32 [100'000, 10]; out: float32 [100'000, 128]
//
// Layout: 32 lanes per row (each lane = one float4 of the 128-dim feature).
// 256-thread block -> 8 rows/block. Gather loads are 512B contiguous per
// (row, neighbor) -> fully coalesced. Indices hoisted to registers for MLP.

#define FEAT_DIM   128
#define NUM_SAMPLE 10
#define QUADS      (FEAT_DIM / 4)       // 32 lanes per row
#define ROWS_PER_BLOCK (256 / QUADS)    // 8

__global__ __launch_bounds__(256) void MeanAggregator_13846974562846_kernel(
    const float* __restrict__ feats,
    const int*   __restrict__ idx,
    float*       __restrict__ out,
    int batch)
{
    const int row  = blockIdx.x * ROWS_PER_BLOCK + (threadIdx.x >> 5);
    const int quad = threadIdx.x & (QUADS - 1);
    if (row >= batch) return;

    // Hoist the 10 neighbor indices into registers (same address across the
    // 32-lane group -> HW coalesces/broadcasts; L1-resident after first touch).
    const int* __restrict__ rid = idx + (long long)row * NUM_SAMPLE;
    int nid[NUM_SAMPLE];
#pragma unroll
    for (int s = 0; s < NUM_SAMPLE; ++s) nid[s] = rid[s];

    float4 acc = make_float4(0.f, 0.f, 0.f, 0.f);
#pragma unroll
    for (int s = 0; s < NUM_SAMPLE; ++s) {
        const float4* __restrict__ src =
            reinterpret_cast<const float4*>(feats + (long long)nid[s] * FEAT_DIM) + quad;
        float4 v = *src;
        acc.x += v.x; acc.y += v.y; acc.z += v.z; acc.w += v.w;
    }

    const float inv = 1.0f / (float)NUM_SAMPLE;
    acc.x *= inv; acc.y *= inv; acc.z *= inv; acc.w *= inv;

    reinterpret_cast<float4*>(out + (long long)row * FEAT_DIM)[quad] = acc;
}

extern "C" void kernel_launch(void* const* d_in, const int* in_sizes, int n_in,
                              void* d_out, int out_size, void* d_ws, size_t ws_size,
                              hipStream_t stream)
{
    const float* feats = (const float*)d_in[0];   // [N_NODES * FEAT_DIM]
    const int*   idx   = (const int*)d_in[1];     // [BATCH * NUM_SAMPLE]
    float*       out   = (float*)d_out;           // [BATCH * FEAT_DIM]

    const int batch = in_sizes[1] / NUM_SAMPLE;   // 100'000

    dim3 block(256);
    dim3 grid((batch + ROWS_PER_BLOCK - 1) / ROWS_PER_BLOCK);
    MeanAggregator_13846974562846_kernel<<<grid, block, 0, stream>>>(feats, idx, out, batch);
}

// Round 3
// 86.213 us; speedup vs baseline: 1.0045x; 1.0045x over previous
//
#include <hip/hip_runtime.h>

// MeanAggregator: out[b, :] = mean_{s<10} features[idx[b,s], :]
// features: float32 [1'000'000, 128]; idx: int32 [100'000, 10]; out: float32 [100'000, 128]
//
// Layout: 32 lanes per row (each lane = one float4 of the 128-dim feature).
// 256-thread block -> 8 rows/block. Gather loads are 512B contiguous per
// (row, neighbor) -> fully coalesced, full cache lines, no over-fetch.
// Non-temporal output stores (streamed-once, 51 MB) so they don't allocate
// in L2/L3 and evict gather lines serving duplicate-index hits.
// R3 fix: use native clang vector type for __builtin_nontemporal_store
// (HIP's float4 is a class -> rejected by the builtin).

#define FEAT_DIM   128
#define NUM_SAMPLE 10
#define QUADS      (FEAT_DIM / 4)       // 32 lanes per row
#define ROWS_PER_BLOCK (256 / QUADS)    // 8

typedef float floatx4 __attribute__((ext_vector_type(4)));

__global__ __launch_bounds__(256) void MeanAggregator_13846974562846_kernel(
    const float* __restrict__ feats,
    const int*   __restrict__ idx,
    float*       __restrict__ out,
    int batch)
{
    const int row  = blockIdx.x * ROWS_PER_BLOCK + (threadIdx.x >> 5);
    const int quad = threadIdx.x & (QUADS - 1);
    if (row >= batch) return;

    // Hoist the 10 neighbor indices into registers (uniform address across the
    // 32-lane group -> broadcast; keeps 10 gather loads in flight below).
    const int* __restrict__ rid = idx + (long long)row * NUM_SAMPLE;
    int nid[NUM_SAMPLE];
#pragma unroll
    for (int s = 0; s < NUM_SAMPLE; ++s) nid[s] = rid[s];

    floatx4 acc = (floatx4)0.0f;
#pragma unroll
    for (int s = 0; s < NUM_SAMPLE; ++s) {
        const floatx4* __restrict__ src =
            reinterpret_cast<const floatx4*>(feats + (long long)nid[s] * FEAT_DIM) + quad;
        acc += *src;
    }

    acc *= (1.0f / (float)NUM_SAMPLE);

    // Non-temporal store: output is written once and never re-read by this
    // kernel -> keep it out of L2/L3 so gather dedupe lines survive.
    floatx4* dst = reinterpret_cast<floatx4*>(out + (long long)row * FEAT_DIM) + quad;
    __builtin_nontemporal_store(acc, dst);
}

extern "C" void kernel_launch(void* const* d_in, const int* in_sizes, int n_in,
                              void* d_out, int out_size, void* d_ws, size_t ws_size,
                              hipStream_t stream)
{
    const float* feats = (const float*)d_in[0];   // [N_NODES * FEAT_DIM]
    const int*   idx   = (const int*)d_in[1];     // [BATCH * NUM_SAMPLE]
    float*       out   = (float*)d_out;           // [BATCH * FEAT_DIM]

    const int batch = in_sizes[1] / NUM_SAMPLE;   // 100'000

    dim3 block(256);
    dim3 grid((batch + ROWS_PER_BLOCK - 1) / ROWS_PER_BLOCK);
    MeanAggregator_13846974562846_kernel<<<grid, block, 0, stream>>>(feats, idx, out, batch);
}